// Round 2
// baseline (193.643 us; speedup 1.0000x reference)
//
#include <hip/hip_runtime.h>
#include <hip/hip_cooperative_groups.h>

namespace cg = cooperative_groups;

// CNF vector field + exact divergence via bilinear-form trick, MFMA edition.
//   dx  = tanh(tanh([x,t]W1+b1)W2+b2)W3+b3, /2
//   div = 0.5 * d1^T (W2 ∘ (W1[:64]^T W3^T)) d2
// Phase 2 = 16x512 @ 512x1024 bf16 GEMM: A=[h1(8);d1(8)], B=[W2|G] packed bf16.
// R6: ~60us of total is harness residue (d_ws 0xAA fill ~41us + restores).
// R7 (97.1us): __launch_bounds__(512,2), ping-pong prefetch (16 b128 in flight).
// R8 FAILED (105.6us): 4-kernel split. Launch gaps + lost block-level phase
//   overlap + C round-trip cost more than the saved L2 B-reads. Reverted.
// R9: merge the pack kernel INTO the fused kernel (cooperative launch, grid
//   256 = 1 block/CU). Each block packs 4 B-chunks on waves 2-5 BEFORE its
//   layer-1 work; one grid.sync() replaces the kernel boundary. Removes one
//   launch gap + hides pack wall time under phase 1.

constexpr int HD = 512;
constexpr int DD = 64;
constexpr int SB = 8;
constexpr int NB = 2048 / SB;   // 256 blocks

typedef __attribute__((ext_vector_type(8))) short bf16x8;
typedef __attribute__((ext_vector_type(4))) float f32x4;

__device__ inline unsigned short f2bf(float f) {
    union { float f; unsigned u; } v; v.f = f;
    return (unsigned short)((v.u + 0x7fffu + ((v.u >> 16) & 1u)) >> 16);
}
__device__ inline float fast_tanh(float xx) {
    float e = __expf(2.f * xx);
    return 1.f - 2.f / (e + 1.f);
}

// Bpack layout (verified R5/R6): chunk c = (mat*32 + t)*16 + kk; lane l holds
// 8 bf16 = B[kk*32+(l>>4)*8+j][t*16+(l&15)], B = W2 (mat 0) or G (mat 1).
// Block b packs chunks {2b, 2b+1} (W2, waves 4-5) and {512+2b, 512+2b+1}
// (G, waves 2-3). Both G chunks share t = (2b)>>4 and use W1 cols
// kbase..kbase+64 where kbase = ((2b)&15)*32.

__global__ __launch_bounds__(512, 2) void cnf_mega_kernel(
    const float* __restrict__ tptr, const float* __restrict__ x,
    const float* __restrict__ W1, const float* __restrict__ b1,
    const float* __restrict__ W2, const float* __restrict__ b2v,
    const float* __restrict__ W3, const float* __restrict__ b3,
    unsigned short* Bpack, float* __restrict__ out)
{
    __shared__ float4 xsv[65 * 2];             // [i][s0-3],[i][s4-7]
    __shared__ unsigned short A_lds[16][520];  // bf16 A; stride 1040B (16B-aligned)
    __shared__ float4 h2v[HD * 2];             // [m][q]
    __shared__ float4 divred[8][2];
    __shared__ float sm_b2[HD];
    __shared__ float w1s[64][65];              // W1[i][kbase+k], pack staging
    __shared__ float w3s[16][68];              // W3[tG*16+nn][i], 16B-aligned rows

    const int tid  = threadIdx.x;
    const int bidx = blockIdx.x;
    const int s0   = bidx * SB;
    const int wave = tid >> 6, lane = tid & 63;
    const int kbase = ((2 * bidx) & 15) * 32;
    const int tG    = (2 * bidx) >> 4;         // 0..31

    // ---- phase 0: stage x rows (drop col 64, append t) + b2 + pack operands --
    {
        const float tval = tptr[0];
        for (int e = tid; e < SB * 65; e += 512) {
            int s = e / 65, i = e % 65;
            reinterpret_cast<float*>(xsv)[i * SB + s] =
                (i == DD) ? tval : x[(s0 + s) * 65 + i];
        }
        sm_b2[tid] = b2v[tid];
        for (int e = tid; e < 64 * 64; e += 512) {       // 8 per thread
            int i = e >> 6, k = e & 63;
            w1s[i][k] = W1[i * HD + kbase + k];
        }
        for (int e = tid; e < 16 * 64; e += 512) {       // 2 per thread
            int nn = e >> 6, i = e & 63;
            w3s[nn][i] = W3[(tG * 16 + nn) * DD + i];
        }
    }
    __syncthreads();

    // ---- phase 0.5: pack 4 B-chunks (waves 2-5); waves 0-1,6-7 skip ahead ----
    if (wave >= 2 && wave < 6) {
        const int q = lane >> 4, nl = lane & 15;
        unsigned short o[8];
        int c;
        if (wave >= 4) {                       // W2 chunks: pure elementwise
            c = 2 * bidx + (wave - 4);
            const int t = (c >> 4) & 31, kk = c & 15;
            const int n = t * 16 + nl;
#pragma unroll
            for (int j = 0; j < 8; ++j)
                o[j] = f2bf(W2[(kk * 32 + q * 8 + j) * HD + n]);
        } else {                               // G chunks: W2 ∘ (W1^T W3^T)
            const int u = wave - 2;
            c = 512 + 2 * bidx + u;
            const int kk = (2 * bidx + u) & 15;
            const int n = tG * 16 + nl;
            float w3r[64];                     // register-cached W3 row
#pragma unroll
            for (int i4 = 0; i4 < 16; ++i4) {
                float4 v = *reinterpret_cast<const float4*>(&w3s[nl][i4 * 4]);
                w3r[i4 * 4]     = v.x; w3r[i4 * 4 + 1] = v.y;
                w3r[i4 * 4 + 2] = v.z; w3r[i4 * 4 + 3] = v.w;
            }
#pragma unroll
            for (int j = 0; j < 8; ++j) {
                const int kloc = u * 32 + q * 8 + j;
                float m = 0.f;
#pragma unroll 8
                for (int i = 0; i < 64; ++i) m += w1s[i][kloc] * w3r[i];
                o[j] = f2bf(W2[(kk * 32 + q * 8 + j) * HD + n] * m);
            }
        }
        uint4 pk;
        pk.x = (unsigned)o[0] | ((unsigned)o[1] << 16);
        pk.y = (unsigned)o[2] | ((unsigned)o[3] << 16);
        pk.z = (unsigned)o[4] | ((unsigned)o[5] << 16);
        pk.w = (unsigned)o[6] | ((unsigned)o[7] << 16);
        reinterpret_cast<uint4*>(Bpack)[c * 64 + lane] = pk;
    }

    // ---- phase 1: layer 1 fp32; thread = unit u, all 8 samples ----
    {
        const int u = tid;
        const float bb = b1[u];
        float2 a0 = {bb, bb}, a1 = {bb, bb}, a2 = {bb, bb}, a3 = {bb, bb};
        for (int ib = 0; ib < 64; ib += 8) {
            float w[8];
#pragma unroll
            for (int qq = 0; qq < 8; ++qq) w[qq] = W1[(ib + qq) * HD + u];
#pragma unroll
            for (int qq = 0; qq < 8; ++qq) {
                float4 p = xsv[2 * (ib + qq)], r = xsv[2 * (ib + qq) + 1];
                a0.x += p.x * w[qq]; a0.y += p.y * w[qq];
                a1.x += p.z * w[qq]; a1.y += p.w * w[qq];
                a2.x += r.x * w[qq]; a2.y += r.y * w[qq];
                a3.x += r.z * w[qq]; a3.y += r.w * w[qq];
            }
        }
        {
            float w = W1[64 * HD + u];
            float4 p = xsv[128], r = xsv[129];
            a0.x += p.x * w; a0.y += p.y * w;
            a1.x += p.z * w; a1.y += p.w * w;
            a2.x += r.x * w; a2.y += r.y * w;
            a3.x += r.z * w; a3.y += r.w * w;
        }
        float h[8] = {fast_tanh(a0.x), fast_tanh(a0.y), fast_tanh(a1.x), fast_tanh(a1.y),
                      fast_tanh(a2.x), fast_tanh(a2.y), fast_tanh(a3.x), fast_tanh(a3.y)};
#pragma unroll
        for (int s = 0; s < 8; ++s) {
            A_lds[s][u]     = f2bf(h[s]);
            A_lds[8 + s][u] = f2bf(1.f - h[s] * h[s]);
        }
    }

    // ---- grid-wide barrier: all Bpack chunks visible, A_lds complete ----
    __threadfence();
    cg::this_grid().sync();

    // ---- phase 2: MFMA. wave w: cols [w*64, w*64+64) of BOTH W2 and G ----
    f32x4 cw[4], cg_[4];
#pragma unroll
    for (int i = 0; i < 4; ++i) { cw[i] = (f32x4){0,0,0,0}; cg_[i] = (f32x4){0,0,0,0}; }
    {
        const unsigned short* arow = &A_lds[lane & 15][0];
        const int aoff = (lane >> 4) * 8;   // ushorts
        const bf16x8* bw = reinterpret_cast<const bf16x8*>(Bpack)
                         + (size_t)(wave * 64) * 64 + lane;
        const bf16x8* bg = bw + 32768;      // + 32 tiles * 1024 frags

        bf16x8 pA[16], pB[16];              // ping-pong super-batches (2 kk each)
        auto loadSB = [&](bf16x8* d, int kk) {
#pragma unroll
            for (int i = 0; i < 4; ++i) {
                d[i]      = bw[kk * 64 + i * 1024];
                d[4 + i]  = bg[kk * 64 + i * 1024];
                d[8 + i]  = bw[(kk + 1) * 64 + i * 1024];
                d[12 + i] = bg[(kk + 1) * 64 + i * 1024];
            }
        };
        auto mfmaSB = [&](const bf16x8* d, int kk) {
            bf16x8 af0 = *reinterpret_cast<const bf16x8*>(arow + kk * 32 + aoff);
#pragma unroll
            for (int i = 0; i < 4; ++i)
                cw[i] = __builtin_amdgcn_mfma_f32_16x16x32_bf16(af0, d[i], cw[i], 0, 0, 0);
#pragma unroll
            for (int i = 0; i < 4; ++i)
                cg_[i] = __builtin_amdgcn_mfma_f32_16x16x32_bf16(af0, d[4 + i], cg_[i], 0, 0, 0);
            bf16x8 af1 = *reinterpret_cast<const bf16x8*>(arow + (kk + 1) * 32 + aoff);
#pragma unroll
            for (int i = 0; i < 4; ++i)
                cw[i] = __builtin_amdgcn_mfma_f32_16x16x32_bf16(af1, d[8 + i], cw[i], 0, 0, 0);
#pragma unroll
            for (int i = 0; i < 4; ++i)
                cg_[i] = __builtin_amdgcn_mfma_f32_16x16x32_bf16(af1, d[12 + i], cg_[i], 0, 0, 0);
        };

        loadSB(pA, 0);
#pragma unroll
        for (int kb = 0; kb < 8; ++kb) {
            bf16x8* cur = (kb & 1) ? pB : pA;
            bf16x8* nxt = (kb & 1) ? pA : pB;
            if (kb < 7) loadSB(nxt, (kb + 1) * 2);
            mfmaSB(cur, kb * 2);
        }
    }

    // ---- epilogue: h2 (lanes 0-31 rows) + div partials (lanes 32-63 rows) ----
    {
        const int q = lane >> 4;                  // row-quad 0..3
        const int src = (lane >= 32) ? lane - 32 : lane;
        float4 dp = {0.f, 0.f, 0.f, 0.f};
#pragma unroll
        for (int i = 0; i < 4; ++i) {
            const int m = wave * 64 + i * 16 + (lane & 15);
            const float bb = sm_b2[m];
            float4 hv;
            hv.x = fast_tanh(cw[i][0] + bb);
            hv.y = fast_tanh(cw[i][1] + bb);
            hv.z = fast_tanh(cw[i][2] + bb);
            hv.w = fast_tanh(cw[i][3] + bb);
            if (lane < 32) h2v[2 * m + q] = hv;   // rows 0-7 = h-samples
            float h0 = __shfl(hv.x, src), h1s = __shfl(hv.y, src);
            float h2s = __shfl(hv.z, src), h3s = __shfl(hv.w, src);
            dp.x += cg_[i][0] * (1.f - h0 * h0);
            dp.y += cg_[i][1] * (1.f - h1s * h1s);
            dp.z += cg_[i][2] * (1.f - h2s * h2s);
            dp.w += cg_[i][3] * (1.f - h3s * h3s);
        }
        if (lane >= 32) {
#pragma unroll
            for (int off = 8; off > 0; off >>= 1) {
                dp.x += __shfl_down(dp.x, off, 16);
                dp.y += __shfl_down(dp.y, off, 16);
                dp.z += __shfl_down(dp.z, off, 16);
                dp.w += __shfl_down(dp.w, off, 16);
            }
            if ((lane & 15) == 0) divred[wave][q - 2] = dp;
        }
    }
    __syncthreads();   // h2v + divred complete; A_lds free

    float* opart = reinterpret_cast<float*>(A_lds);   // 8 x 512 fp32

    // ---- phase 4: layer 3 fp32; part = wave, k = lane; 64 m's per part ----
    {
        const int k = lane, part = wave;
        float o[8];
#pragma unroll
        for (int q = 0; q < 8; ++q) o[q] = 0.f;
        const int mb = part * 64;
        for (int mm = 0; mm < 64; mm += 4) {
            float w[4];
#pragma unroll
            for (int q = 0; q < 4; ++q) w[q] = W3[(mb + mm + q) * DD + k];
#pragma unroll
            for (int q = 0; q < 4; ++q) {
                const int m = mb + mm + q;
                float4 ha = h2v[2 * m], hb = h2v[2 * m + 1];
                o[0] += ha.x * w[q]; o[1] += ha.y * w[q];
                o[2] += ha.z * w[q]; o[3] += ha.w * w[q];
                o[4] += hb.x * w[q]; o[5] += hb.y * w[q];
                o[6] += hb.z * w[q]; o[7] += hb.w * w[q];
            }
        }
#pragma unroll
        for (int q = 0; q < 8; ++q) opart[part * 512 + q * 64 + k] = o[q];
    }
    __syncthreads();

    // ---- outputs ----
    {
        const int s = tid >> 6, k = tid & 63;
        float sum = b3[k];
#pragma unroll
        for (int p = 0; p < 8; ++p) sum += opart[p * 512 + s * 64 + k];
        out[(s0 + s) * 65 + k] = 0.5f * sum;
    }
    if (tid < 8) {
        const int qq = tid >> 2, r = tid & 3;
        float ds = 0.f;
#pragma unroll
        for (int w = 0; w < 8; ++w)
            ds += reinterpret_cast<const float*>(&divred[w][qq])[r];
        out[(s0 + tid) * 65 + DD] = 0.5f * ds;
    }
}

extern "C" void kernel_launch(void* const* d_in, const int* in_sizes, int n_in,
                              void* d_out, int out_size, void* d_ws, size_t ws_size,
                              hipStream_t stream) {
    const float* t  = (const float*)d_in[0];
    const float* x  = (const float*)d_in[1];
    const float* W1 = (const float*)d_in[2];
    const float* b1 = (const float*)d_in[3];
    const float* W2 = (const float*)d_in[4];
    const float* b2 = (const float*)d_in[5];
    const float* W3 = (const float*)d_in[6];
    const float* b3 = (const float*)d_in[7];
    float* out = (float*)d_out;
    unsigned short* Bpack = (unsigned short*)d_ws;   // 2*512*512 bf16 = 1 MB

    void* args[] = {(void*)&t,  (void*)&x,  (void*)&W1, (void*)&b1, (void*)&W2,
                    (void*)&b2, (void*)&W3, (void*)&b3, (void*)&Bpack, (void*)&out};
    hipLaunchCooperativeKernel((const void*)cnf_mega_kernel, dim3(NB), dim3(512),
                               args, 0, stream);
}

// Round 3
// 100.458 us; speedup vs baseline: 1.9276x; 1.9276x over previous
//
#include <hip/hip_runtime.h>

// CNF vector field + exact divergence via bilinear-form trick, MFMA edition.
//   dx  = tanh(tanh([x,t]W1+b1)W2+b2)W3+b3, /2
//   div = 0.5 * d1^T (W2 ∘ (W1[:64]^T W3^T)) d2
// Phase 2 = 16x512 @ 512x1024 bf16 GEMM: A=[h1(8);d1(8)], B=[W2|G] packed bf16.
// R6: ~60us of total is harness residue (d_ws 0xAA fill ~41us + restores).
// R7 (97.1us, BEST): __launch_bounds__(512,2) fused kernel, ping-pong prefetch.
// R8 FAILED (105.6us): 4-kernel split — launch gaps + lost phase overlap.
// R9 FAILED (193.6us): cooperative mega-kernel — merging pack+fused into one
//   function wrecked regalloc (VGPR 68 => 128-VGPR prefetch buffers spilled to
//   scratch; kernel alone 105us, all pipes idle). Phases want separate kernels.
// R10: fused kernel reverted to EXACT R7. Pack mat=1 path only: W3 row cached
//   in registers + loop nest swapped so W1 reads are 2x ds_read_b128 per i
//   (was 1024 scalar b32/thread -> 128 b128). Same accumulation order =>
//   bit-identical G.

constexpr int HD = 512;
constexpr int DD = 64;
constexpr int SB = 8;
constexpr int NB = 2048 / SB;   // 256 blocks

typedef __attribute__((ext_vector_type(8))) short bf16x8;
typedef __attribute__((ext_vector_type(4))) float f32x4;

__device__ inline unsigned short f2bf(float f) {
    union { float f; unsigned u; } v; v.f = f;
    return (unsigned short)((v.u + 0x7fffu + ((v.u >> 16) & 1u)) >> 16);
}
__device__ inline float fast_tanh(float xx) {
    float e = __expf(2.f * xx);
    return 1.f - 2.f / (e + 1.f);
}

// ---------------- pack kernel: Bpack = bf16 fragment-ordered [W2 | G] --------
// chunk c = (mat*32 + t)*16 + kk; lane l: 8 bf16 = B[kk*32+(l>>4)*8+j][t*16+(l&15)]
// (layout verified R5/R6: absmax 3.9e-3). mat 1 computes G inline.
__global__ __launch_bounds__(64) void cnf_pack_kernel(
    const float* __restrict__ W1, const float* __restrict__ W2,
    const float* __restrict__ W3, unsigned short* __restrict__ Bpack)
{
    __shared__ float w1s[64][36];   // stride 144B: 16B-aligned float4 rows
    __shared__ float w3s[16][68];   // stride 272B: 16B-aligned float4 rows
    const int b = blockIdx.x;                 // 0..1023
    const int mat = b >> 9, t = (b >> 4) & 31, kk = b & 15;
    const int l = threadIdx.x;
    const int q = l >> 4, nl = l & 15;
    const int n = t * 16 + nl;
    unsigned short o[8];
    if (mat == 0) {
#pragma unroll
        for (int j = 0; j < 8; ++j) {
            int k = kk * 32 + q * 8 + j;
            o[j] = f2bf(W2[k * HD + n]);
        }
    } else {
        for (int e = l; e < 64 * 32; e += 64) {
            int i = e >> 5, kl = e & 31;
            w1s[i][kl] = W1[i * HD + kk * 32 + kl];
        }
        for (int e = l; e < 16 * 64; e += 64) {
            int nn = e >> 6, i = e & 63;
            w3s[nn][i] = W3[(t * 16 + nn) * DD + i];
        }
        __syncthreads();
        // register-cache this lane's W3 row (removes half the LDS reads)
        float w3r[64];
#pragma unroll
        for (int i4 = 0; i4 < 16; ++i4) {
            float4 v = *reinterpret_cast<const float4*>(&w3s[nl][i4 * 4]);
            w3r[i4 * 4]     = v.x; w3r[i4 * 4 + 1] = v.y;
            w3r[i4 * 4 + 2] = v.z; w3r[i4 * 4 + 3] = v.w;
        }
        // i-outer: 2x b128 W1 reads per i (4-address broadcast, conflict-free);
        // per-j accumulation order identical to R7 (i ascending) => bit-identical
        float m8[8] = {0.f, 0.f, 0.f, 0.f, 0.f, 0.f, 0.f, 0.f};
#pragma unroll 4
        for (int i = 0; i < 64; ++i) {
            const float wv = w3r[i];
            float4 a = *reinterpret_cast<const float4*>(&w1s[i][q * 8]);
            float4 c = *reinterpret_cast<const float4*>(&w1s[i][q * 8 + 4]);
            m8[0] += a.x * wv; m8[1] += a.y * wv; m8[2] += a.z * wv; m8[3] += a.w * wv;
            m8[4] += c.x * wv; m8[5] += c.y * wv; m8[6] += c.z * wv; m8[7] += c.w * wv;
        }
#pragma unroll
        for (int j = 0; j < 8; ++j)
            o[j] = f2bf(W2[(kk * 32 + q * 8 + j) * HD + n] * m8[j]);
    }
    uint4 pk;
    pk.x = (unsigned)o[0] | ((unsigned)o[1] << 16);
    pk.y = (unsigned)o[2] | ((unsigned)o[3] << 16);
    pk.z = (unsigned)o[4] | ((unsigned)o[5] << 16);
    pk.w = (unsigned)o[6] | ((unsigned)o[7] << 16);
    reinterpret_cast<uint4*>(Bpack)[b * 64 + l] = pk;
}

// ---------------- fused MLP + divergence, 512 threads (EXACT R7) -------------
__global__ __launch_bounds__(512, 2) void cnf_fused_kernel(
    const float* __restrict__ tptr, const float* __restrict__ x,
    const float* __restrict__ W1, const float* __restrict__ b1,
    const float* __restrict__ b2v, const float* __restrict__ W3,
    const float* __restrict__ b3, const unsigned short* __restrict__ Bpack,
    float* __restrict__ out)
{
    __shared__ float4 xsv[65 * 2];             // [i][s0-3],[i][s4-7]
    __shared__ unsigned short A_lds[16][520];  // bf16 A; stride 1040B (16B-aligned)
    __shared__ float4 h2v[HD * 2];             // [m][q]
    __shared__ float4 divred[8][2];
    __shared__ float sm_b2[HD];

    const int tid  = threadIdx.x;
    const int s0   = blockIdx.x * SB;
    const int wave = tid >> 6, lane = tid & 63;

    // ---- phase 0: stage x rows (drop col 64, append t) + b2 ----
    {
        const float tval = tptr[0];
        for (int e = tid; e < SB * 65; e += 512) {
            int s = e / 65, i = e % 65;
            reinterpret_cast<float*>(xsv)[i * SB + s] =
                (i == DD) ? tval : x[(s0 + s) * 65 + i];
        }
        sm_b2[tid] = b2v[tid];
    }
    __syncthreads();

    // ---- phase 1: layer 1 fp32; thread = unit u, all 8 samples ----
    {
        const int u = tid;
        const float bb = b1[u];
        float2 a0 = {bb, bb}, a1 = {bb, bb}, a2 = {bb, bb}, a3 = {bb, bb};
        for (int ib = 0; ib < 64; ib += 8) {
            float w[8];
#pragma unroll
            for (int qq = 0; qq < 8; ++qq) w[qq] = W1[(ib + qq) * HD + u];
#pragma unroll
            for (int qq = 0; qq < 8; ++qq) {
                float4 p = xsv[2 * (ib + qq)], r = xsv[2 * (ib + qq) + 1];
                a0.x += p.x * w[qq]; a0.y += p.y * w[qq];
                a1.x += p.z * w[qq]; a1.y += p.w * w[qq];
                a2.x += r.x * w[qq]; a2.y += r.y * w[qq];
                a3.x += r.z * w[qq]; a3.y += r.w * w[qq];
            }
        }
        {
            float w = W1[64 * HD + u];
            float4 p = xsv[128], r = xsv[129];
            a0.x += p.x * w; a0.y += p.y * w;
            a1.x += p.z * w; a1.y += p.w * w;
            a2.x += r.x * w; a2.y += r.y * w;
            a3.x += r.z * w; a3.y += r.w * w;
        }
        float h[8] = {fast_tanh(a0.x), fast_tanh(a0.y), fast_tanh(a1.x), fast_tanh(a1.y),
                      fast_tanh(a2.x), fast_tanh(a2.y), fast_tanh(a3.x), fast_tanh(a3.y)};
#pragma unroll
        for (int s = 0; s < 8; ++s) {
            A_lds[s][u]     = f2bf(h[s]);
            A_lds[8 + s][u] = f2bf(1.f - h[s] * h[s]);
        }
    }
    __syncthreads();

    // ---- phase 2: MFMA. wave w: cols [w*64, w*64+64) of BOTH W2 and G ----
    f32x4 cw[4], cg[4];
#pragma unroll
    for (int i = 0; i < 4; ++i) { cw[i] = (f32x4){0,0,0,0}; cg[i] = (f32x4){0,0,0,0}; }
    {
        const unsigned short* arow = &A_lds[lane & 15][0];
        const int aoff = (lane >> 4) * 8;   // ushorts
        const bf16x8* bw = reinterpret_cast<const bf16x8*>(Bpack)
                         + (size_t)(wave * 64) * 64 + lane;
        const bf16x8* bg = bw + 32768;      // + 32 tiles * 1024 frags

        bf16x8 pA[16], pB[16];              // ping-pong super-batches (2 kk each)
        auto loadSB = [&](bf16x8* d, int kk) {
#pragma unroll
            for (int i = 0; i < 4; ++i) {
                d[i]      = bw[kk * 64 + i * 1024];
                d[4 + i]  = bg[kk * 64 + i * 1024];
                d[8 + i]  = bw[(kk + 1) * 64 + i * 1024];
                d[12 + i] = bg[(kk + 1) * 64 + i * 1024];
            }
        };
        auto mfmaSB = [&](const bf16x8* d, int kk) {
            bf16x8 af0 = *reinterpret_cast<const bf16x8*>(arow + kk * 32 + aoff);
#pragma unroll
            for (int i = 0; i < 4; ++i)
                cw[i] = __builtin_amdgcn_mfma_f32_16x16x32_bf16(af0, d[i], cw[i], 0, 0, 0);
#pragma unroll
            for (int i = 0; i < 4; ++i)
                cg[i] = __builtin_amdgcn_mfma_f32_16x16x32_bf16(af0, d[4 + i], cg[i], 0, 0, 0);
            bf16x8 af1 = *reinterpret_cast<const bf16x8*>(arow + (kk + 1) * 32 + aoff);
#pragma unroll
            for (int i = 0; i < 4; ++i)
                cw[i] = __builtin_amdgcn_mfma_f32_16x16x32_bf16(af1, d[8 + i], cw[i], 0, 0, 0);
#pragma unroll
            for (int i = 0; i < 4; ++i)
                cg[i] = __builtin_amdgcn_mfma_f32_16x16x32_bf16(af1, d[12 + i], cg[i], 0, 0, 0);
        };

        loadSB(pA, 0);
#pragma unroll
        for (int kb = 0; kb < 8; ++kb) {
            bf16x8* cur = (kb & 1) ? pB : pA;
            bf16x8* nxt = (kb & 1) ? pA : pB;
            if (kb < 7) loadSB(nxt, (kb + 1) * 2);
            mfmaSB(cur, kb * 2);
        }
    }

    // ---- epilogue: h2 (lanes 0-31 rows) + div partials (lanes 32-63 rows) ----
    {
        const int q = lane >> 4;                  // row-quad 0..3
        const int src = (lane >= 32) ? lane - 32 : lane;
        float4 dp = {0.f, 0.f, 0.f, 0.f};
#pragma unroll
        for (int i = 0; i < 4; ++i) {
            const int m = wave * 64 + i * 16 + (lane & 15);
            const float bb = sm_b2[m];
            float4 hv;
            hv.x = fast_tanh(cw[i][0] + bb);
            hv.y = fast_tanh(cw[i][1] + bb);
            hv.z = fast_tanh(cw[i][2] + bb);
            hv.w = fast_tanh(cw[i][3] + bb);
            if (lane < 32) h2v[2 * m + q] = hv;   // rows 0-7 = h-samples
            float h0 = __shfl(hv.x, src), h1s = __shfl(hv.y, src);
            float h2s = __shfl(hv.z, src), h3s = __shfl(hv.w, src);
            dp.x += cg[i][0] * (1.f - h0 * h0);
            dp.y += cg[i][1] * (1.f - h1s * h1s);
            dp.z += cg[i][2] * (1.f - h2s * h2s);
            dp.w += cg[i][3] * (1.f - h3s * h3s);
        }
        if (lane >= 32) {
#pragma unroll
            for (int off = 8; off > 0; off >>= 1) {
                dp.x += __shfl_down(dp.x, off, 16);
                dp.y += __shfl_down(dp.y, off, 16);
                dp.z += __shfl_down(dp.z, off, 16);
                dp.w += __shfl_down(dp.w, off, 16);
            }
            if ((lane & 15) == 0) divred[wave][q - 2] = dp;
        }
    }
    __syncthreads();   // h2v + divred complete; A_lds free

    float* opart = reinterpret_cast<float*>(A_lds);   // 8 x 512 fp32

    // ---- phase 4: layer 3 fp32; part = wave, k = lane; 64 m's per part ----
    {
        const int k = lane, part = wave;
        float o[8];
#pragma unroll
        for (int q = 0; q < 8; ++q) o[q] = 0.f;
        const int mb = part * 64;
        for (int mm = 0; mm < 64; mm += 4) {
            float w[4];
#pragma unroll
            for (int q = 0; q < 4; ++q) w[q] = W3[(mb + mm + q) * DD + k];
#pragma unroll
            for (int q = 0; q < 4; ++q) {
                const int m = mb + mm + q;
                float4 ha = h2v[2 * m], hb = h2v[2 * m + 1];
                o[0] += ha.x * w[q]; o[1] += ha.y * w[q];
                o[2] += ha.z * w[q]; o[3] += ha.w * w[q];
                o[4] += hb.x * w[q]; o[5] += hb.y * w[q];
                o[6] += hb.z * w[q]; o[7] += hb.w * w[q];
            }
        }
#pragma unroll
        for (int q = 0; q < 8; ++q) opart[part * 512 + q * 64 + k] = o[q];
    }
    __syncthreads();

    // ---- outputs ----
    {
        const int s = tid >> 6, k = tid & 63;
        float sum = b3[k];
#pragma unroll
        for (int p = 0; p < 8; ++p) sum += opart[p * 512 + s * 64 + k];
        out[(s0 + s) * 65 + k] = 0.5f * sum;
    }
    if (tid < 8) {
        const int qq = tid >> 2, r = tid & 3;
        float ds = 0.f;
#pragma unroll
        for (int w = 0; w < 8; ++w)
            ds += reinterpret_cast<const float*>(&divred[w][qq])[r];
        out[(s0 + tid) * 65 + DD] = 0.5f * ds;
    }
}

extern "C" void kernel_launch(void* const* d_in, const int* in_sizes, int n_in,
                              void* d_out, int out_size, void* d_ws, size_t ws_size,
                              hipStream_t stream) {
    const float* t  = (const float*)d_in[0];
    const float* x  = (const float*)d_in[1];
    const float* W1 = (const float*)d_in[2];
    const float* b1 = (const float*)d_in[3];
    const float* W2 = (const float*)d_in[4];
    const float* b2 = (const float*)d_in[5];
    const float* W3 = (const float*)d_in[6];
    const float* b3 = (const float*)d_in[7];
    float* out = (float*)d_out;
    unsigned short* Bpack = (unsigned short*)d_ws;   // 2*512*512 bf16 = 1 MB

    cnf_pack_kernel<<<1024, 64, 0, stream>>>(W1, W2, W3, Bpack);
    cnf_fused_kernel<<<NB, 512, 0, stream>>>(t, x, W1, b1, b2, W3, b3, Bpack, out);
}

// Round 4
// 98.562 us; speedup vs baseline: 1.9647x; 1.0192x over previous
//
#include <hip/hip_runtime.h>

// CNF vector field + exact divergence via bilinear-form trick, MFMA edition.
//   dx  = tanh(tanh([x,t]W1+b1)W2+b2)W3+b3, /2
//   div = 0.5 * d1^T (W2 ∘ (W1[:64]^T W3^T)) d2
// Phase 2 = 16x512 @ 512x1024 bf16 GEMM: A=[h1(8);d1(8)], B=[W2|G] packed bf16.
// Journal:
//   R7 (97.1us, BEST): __launch_bounds__(512,2) fused + ping-pong prefetch.
//   R8 FAILED (105.6us): 4-kernel split — launch gaps + lost phase overlap +
//     C round-trip outweighed the saved L2 B-reads.
//   R9 FAILED (193.6us): cooperative mega-kernel — merged pack wrecked regalloc
//     (VGPR 68, prefetch buffers spilled to scratch; kernel alone 105us).
//   R10 NEUTRAL/REGRESS (100.5us): pack-path "optimization" (w3r reg-cache +
//     b128 LDS reads) within noise or slightly worse. Reverted.
//   R11: exact R7 restore. Budget arithmetic from R8/R9: harness residue
//     ~86-88us (256MB 0xAA ws-fill 41-44us + ~35us of tiny restore dispatches);
//     fused phase 2 ~7.4us pinned at aggregate-L2 roofline (256 blocks x 1MB
//     Bpack, byte count algorithmically forced); pack+gap ~4.5us, twice shown
//     not worth restructuring. Controllable region ~10us of 97.

constexpr int HD = 512;
constexpr int DD = 64;
constexpr int SB = 8;
constexpr int NB = 2048 / SB;   // 256 blocks

typedef __attribute__((ext_vector_type(8))) short bf16x8;
typedef __attribute__((ext_vector_type(4))) float f32x4;

__device__ inline unsigned short f2bf(float f) {
    union { float f; unsigned u; } v; v.f = f;
    return (unsigned short)((v.u + 0x7fffu + ((v.u >> 16) & 1u)) >> 16);
}
__device__ inline float fast_tanh(float xx) {
    float e = __expf(2.f * xx);
    return 1.f - 2.f / (e + 1.f);
}

// ---------------- pack kernel: Bpack = bf16 fragment-ordered [W2 | G] --------
// chunk c = (mat*32 + t)*16 + kk; lane l: 8 bf16 = B[kk*32+(l>>4)*8+j][t*16+(l&15)]
// (layout verified R5/R6: absmax 3.9e-3). mat 1 computes G inline.
__global__ __launch_bounds__(64) void cnf_pack_kernel(
    const float* __restrict__ W1, const float* __restrict__ W2,
    const float* __restrict__ W3, unsigned short* __restrict__ Bpack)
{
    __shared__ float w1s[64][33];
    __shared__ float w3s[16][65];
    const int b = blockIdx.x;                 // 0..1023
    const int mat = b >> 9, t = (b >> 4) & 31, kk = b & 15;
    const int l = threadIdx.x;
    const int q = l >> 4, nl = l & 15;
    const int n = t * 16 + nl;
    unsigned short o[8];
    if (mat == 0) {
#pragma unroll
        for (int j = 0; j < 8; ++j) {
            int k = kk * 32 + q * 8 + j;
            o[j] = f2bf(W2[k * HD + n]);
        }
    } else {
        for (int e = l; e < 64 * 32; e += 64) {
            int i = e >> 5, kl = e & 31;
            w1s[i][kl] = W1[i * HD + kk * 32 + kl];
        }
        for (int e = l; e < 16 * 64; e += 64) {
            int nn = e >> 6, i = e & 63;
            w3s[nn][i] = W3[(t * 16 + nn) * DD + i];
        }
        __syncthreads();
#pragma unroll
        for (int j = 0; j < 8; ++j) {
            int kl = q * 8 + j;
            float m = 0.f;
#pragma unroll 8
            for (int i = 0; i < 64; ++i) m += w1s[i][kl] * w3s[nl][i];
            o[j] = f2bf(W2[(kk * 32 + kl) * HD + n] * m);
        }
    }
    uint4 pk;
    pk.x = (unsigned)o[0] | ((unsigned)o[1] << 16);
    pk.y = (unsigned)o[2] | ((unsigned)o[3] << 16);
    pk.z = (unsigned)o[4] | ((unsigned)o[5] << 16);
    pk.w = (unsigned)o[6] | ((unsigned)o[7] << 16);
    reinterpret_cast<uint4*>(Bpack)[b * 64 + l] = pk;
}

// ---------------- fused MLP + divergence, 512 threads ----------------
__global__ __launch_bounds__(512, 2) void cnf_fused_kernel(
    const float* __restrict__ tptr, const float* __restrict__ x,
    const float* __restrict__ W1, const float* __restrict__ b1,
    const float* __restrict__ b2v, const float* __restrict__ W3,
    const float* __restrict__ b3, const unsigned short* __restrict__ Bpack,
    float* __restrict__ out)
{
    __shared__ float4 xsv[65 * 2];             // [i][s0-3],[i][s4-7]
    __shared__ unsigned short A_lds[16][520];  // bf16 A; stride 1040B (16B-aligned)
    __shared__ float4 h2v[HD * 2];             // [m][q]
    __shared__ float4 divred[8][2];
    __shared__ float sm_b2[HD];

    const int tid  = threadIdx.x;
    const int s0   = blockIdx.x * SB;
    const int wave = tid >> 6, lane = tid & 63;

    // ---- phase 0: stage x rows (drop col 64, append t) + b2 ----
    {
        const float tval = tptr[0];
        for (int e = tid; e < SB * 65; e += 512) {
            int s = e / 65, i = e % 65;
            reinterpret_cast<float*>(xsv)[i * SB + s] =
                (i == DD) ? tval : x[(s0 + s) * 65 + i];
        }
        sm_b2[tid] = b2v[tid];
    }
    __syncthreads();

    // ---- phase 1: layer 1 fp32; thread = unit u, all 8 samples ----
    {
        const int u = tid;
        const float bb = b1[u];
        float2 a0 = {bb, bb}, a1 = {bb, bb}, a2 = {bb, bb}, a3 = {bb, bb};
        for (int ib = 0; ib < 64; ib += 8) {
            float w[8];
#pragma unroll
            for (int qq = 0; qq < 8; ++qq) w[qq] = W1[(ib + qq) * HD + u];
#pragma unroll
            for (int qq = 0; qq < 8; ++qq) {
                float4 p = xsv[2 * (ib + qq)], r = xsv[2 * (ib + qq) + 1];
                a0.x += p.x * w[qq]; a0.y += p.y * w[qq];
                a1.x += p.z * w[qq]; a1.y += p.w * w[qq];
                a2.x += r.x * w[qq]; a2.y += r.y * w[qq];
                a3.x += r.z * w[qq]; a3.y += r.w * w[qq];
            }
        }
        {
            float w = W1[64 * HD + u];
            float4 p = xsv[128], r = xsv[129];
            a0.x += p.x * w; a0.y += p.y * w;
            a1.x += p.z * w; a1.y += p.w * w;
            a2.x += r.x * w; a2.y += r.y * w;
            a3.x += r.z * w; a3.y += r.w * w;
        }
        float h[8] = {fast_tanh(a0.x), fast_tanh(a0.y), fast_tanh(a1.x), fast_tanh(a1.y),
                      fast_tanh(a2.x), fast_tanh(a2.y), fast_tanh(a3.x), fast_tanh(a3.y)};
#pragma unroll
        for (int s = 0; s < 8; ++s) {
            A_lds[s][u]     = f2bf(h[s]);
            A_lds[8 + s][u] = f2bf(1.f - h[s] * h[s]);
        }
    }
    __syncthreads();

    // ---- phase 2: MFMA. wave w: cols [w*64, w*64+64) of BOTH W2 and G ----
    f32x4 cw[4], cg[4];
#pragma unroll
    for (int i = 0; i < 4; ++i) { cw[i] = (f32x4){0,0,0,0}; cg[i] = (f32x4){0,0,0,0}; }
    {
        const unsigned short* arow = &A_lds[lane & 15][0];
        const int aoff = (lane >> 4) * 8;   // ushorts
        const bf16x8* bw = reinterpret_cast<const bf16x8*>(Bpack)
                         + (size_t)(wave * 64) * 64 + lane;
        const bf16x8* bg = bw + 32768;      // + 32 tiles * 1024 frags

        bf16x8 pA[16], pB[16];              // ping-pong super-batches (2 kk each)
        auto loadSB = [&](bf16x8* d, int kk) {
#pragma unroll
            for (int i = 0; i < 4; ++i) {
                d[i]      = bw[kk * 64 + i * 1024];
                d[4 + i]  = bg[kk * 64 + i * 1024];
                d[8 + i]  = bw[(kk + 1) * 64 + i * 1024];
                d[12 + i] = bg[(kk + 1) * 64 + i * 1024];
            }
        };
        auto mfmaSB = [&](const bf16x8* d, int kk) {
            bf16x8 af0 = *reinterpret_cast<const bf16x8*>(arow + kk * 32 + aoff);
#pragma unroll
            for (int i = 0; i < 4; ++i)
                cw[i] = __builtin_amdgcn_mfma_f32_16x16x32_bf16(af0, d[i], cw[i], 0, 0, 0);
#pragma unroll
            for (int i = 0; i < 4; ++i)
                cg[i] = __builtin_amdgcn_mfma_f32_16x16x32_bf16(af0, d[4 + i], cg[i], 0, 0, 0);
            bf16x8 af1 = *reinterpret_cast<const bf16x8*>(arow + (kk + 1) * 32 + aoff);
#pragma unroll
            for (int i = 0; i < 4; ++i)
                cw[i] = __builtin_amdgcn_mfma_f32_16x16x32_bf16(af1, d[8 + i], cw[i], 0, 0, 0);
#pragma unroll
            for (int i = 0; i < 4; ++i)
                cg[i] = __builtin_amdgcn_mfma_f32_16x16x32_bf16(af1, d[12 + i], cg[i], 0, 0, 0);
        };

        loadSB(pA, 0);
#pragma unroll
        for (int kb = 0; kb < 8; ++kb) {
            bf16x8* cur = (kb & 1) ? pB : pA;
            bf16x8* nxt = (kb & 1) ? pA : pB;
            if (kb < 7) loadSB(nxt, (kb + 1) * 2);
            mfmaSB(cur, kb * 2);
        }
    }

    // ---- epilogue: h2 (lanes 0-31 rows) + div partials (lanes 32-63 rows) ----
    {
        const int q = lane >> 4;                  // row-quad 0..3
        const int src = (lane >= 32) ? lane - 32 : lane;
        float4 dp = {0.f, 0.f, 0.f, 0.f};
#pragma unroll
        for (int i = 0; i < 4; ++i) {
            const int m = wave * 64 + i * 16 + (lane & 15);
            const float bb = sm_b2[m];
            float4 hv;
            hv.x = fast_tanh(cw[i][0] + bb);
            hv.y = fast_tanh(cw[i][1] + bb);
            hv.z = fast_tanh(cw[i][2] + bb);
            hv.w = fast_tanh(cw[i][3] + bb);
            if (lane < 32) h2v[2 * m + q] = hv;   // rows 0-7 = h-samples
            float h0 = __shfl(hv.x, src), h1s = __shfl(hv.y, src);
            float h2s = __shfl(hv.z, src), h3s = __shfl(hv.w, src);
            dp.x += cg[i][0] * (1.f - h0 * h0);
            dp.y += cg[i][1] * (1.f - h1s * h1s);
            dp.z += cg[i][2] * (1.f - h2s * h2s);
            dp.w += cg[i][3] * (1.f - h3s * h3s);
        }
        if (lane >= 32) {
#pragma unroll
            for (int off = 8; off > 0; off >>= 1) {
                dp.x += __shfl_down(dp.x, off, 16);
                dp.y += __shfl_down(dp.y, off, 16);
                dp.z += __shfl_down(dp.z, off, 16);
                dp.w += __shfl_down(dp.w, off, 16);
            }
            if ((lane & 15) == 0) divred[wave][q - 2] = dp;
        }
    }
    __syncthreads();   // h2v + divred complete; A_lds free

    float* opart = reinterpret_cast<float*>(A_lds);   // 8 x 512 fp32

    // ---- phase 4: layer 3 fp32; part = wave, k = lane; 64 m's per part ----
    {
        const int k = lane, part = wave;
        float o[8];
#pragma unroll
        for (int q = 0; q < 8; ++q) o[q] = 0.f;
        const int mb = part * 64;
        for (int mm = 0; mm < 64; mm += 4) {
            float w[4];
#pragma unroll
            for (int q = 0; q < 4; ++q) w[q] = W3[(mb + mm + q) * DD + k];
#pragma unroll
            for (int q = 0; q < 4; ++q) {
                const int m = mb + mm + q;
                float4 ha = h2v[2 * m], hb = h2v[2 * m + 1];
                o[0] += ha.x * w[q]; o[1] += ha.y * w[q];
                o[2] += ha.z * w[q]; o[3] += ha.w * w[q];
                o[4] += hb.x * w[q]; o[5] += hb.y * w[q];
                o[6] += hb.z * w[q]; o[7] += hb.w * w[q];
            }
        }
#pragma unroll
        for (int q = 0; q < 8; ++q) opart[part * 512 + q * 64 + k] = o[q];
    }
    __syncthreads();

    // ---- outputs ----
    {
        const int s = tid >> 6, k = tid & 63;
        float sum = b3[k];
#pragma unroll
        for (int p = 0; p < 8; ++p) sum += opart[p * 512 + s * 64 + k];
        out[(s0 + s) * 65 + k] = 0.5f * sum;
    }
    if (tid < 8) {
        const int qq = tid >> 2, r = tid & 3;
        float ds = 0.f;
#pragma unroll
        for (int w = 0; w < 8; ++w)
            ds += reinterpret_cast<const float*>(&divred[w][qq])[r];
        out[(s0 + tid) * 65 + DD] = 0.5f * ds;
    }
}

extern "C" void kernel_launch(void* const* d_in, const int* in_sizes, int n_in,
                              void* d_out, int out_size, void* d_ws, size_t ws_size,
                              hipStream_t stream) {
    const float* t  = (const float*)d_in[0];
    const float* x  = (const float*)d_in[1];
    const float* W1 = (const float*)d_in[2];
    const float* b1 = (const float*)d_in[3];
    const float* W2 = (const float*)d_in[4];
    const float* b2 = (const float*)d_in[5];
    const float* W3 = (const float*)d_in[6];
    const float* b3 = (const float*)d_in[7];
    float* out = (float*)d_out;
    unsigned short* Bpack = (unsigned short*)d_ws;   // 2*512*512 bf16 = 1 MB

    cnf_pack_kernel<<<1024, 64, 0, stream>>>(W1, W2, W3, Bpack);
    cnf_fused_kernel<<<NB, 512, 0, stream>>>(t, x, W1, b1, b2, W3, b3, Bpack, out);
}